// Round 7
// baseline (279.564 us; speedup 1.0000x reference)
//
#include <hip/hip_runtime.h>
#include <hip/hip_bf16.h>
#include <stdint.h>

#define NN 50000
#define NE 800000
#define NODE_IN 256
#define EDGE_OUT 64
#define GLOBAL_IN 128
#define NODE_OUT 256
#define HIDDEN 512
#define K1 320          // NODE_IN + EDGE_OUT (u-part folded into per-graph bias G)
#define N_GRAPHS 64
#define MAXDEG 64       // Poisson(16) tail: P(deg>64) ~ 1e-18 per node; writes guarded
#define HCH_LD 136      // 128 + 8 pad shorts: 272B row stride -> conflict-free b128 reads

typedef __attribute__((ext_vector_type(8))) short bf16x8;
typedef __attribute__((ext_vector_type(4))) float f32x4;
typedef __attribute__((ext_vector_type(4))) unsigned short us4;

__device__ __forceinline__ unsigned short f2bf(float x) {
    union { float f; unsigned int u; } c; c.f = x;
    unsigned int u = c.u;
    unsigned int r = (u + 0x7FFFu + ((u >> 16) & 1u)) >> 16;
    return (unsigned short)r;
}

#define GLD_LDS(gp, lp) __builtin_amdgcn_global_load_lds( \
    (const __attribute__((address_space(1))) unsigned int*)(gp), \
    (__attribute__((address_space(3))) unsigned int*)(lp), 16, 0, 0)

// ---------------- prep: W1T (K<320), W2T, G = u@W1_u + b1, zero cnt ----------------
#define PREP_W1 (HIDDEN * K1)                 // 163840
#define PREP_W2 (PREP_W1 + NODE_OUT * HIDDEN) // +131072 = 294912
#define PREP_G  (PREP_W2 + N_GRAPHS * HIDDEN) // +32768  = 327680
#define PREP_Z  (PREP_G + NN)                 // +50000  = 377680
__global__ __launch_bounds__(256)
void prep(const float* __restrict__ W1, const float* __restrict__ W2,
          const float* __restrict__ u, const float* __restrict__ b1,
          unsigned short* __restrict__ W1T, unsigned short* __restrict__ W2T,
          float* __restrict__ G, int* __restrict__ cnt)
{
    int idx = blockIdx.x * 256 + threadIdx.x;
    if (idx < PREP_W1) {
        int n = idx / K1, k = idx - n * K1;
        W1T[idx] = f2bf(W1[(size_t)k * HIDDEN + n]);          // W1T[n][k], k<320
    } else if (idx < PREP_W2) {
        int j = idx - PREP_W1;
        int n = j / HIDDEN, k = j - n * HIDDEN;
        W2T[j] = f2bf(W2[(size_t)k * NODE_OUT + n]);
    } else if (idx < PREP_G) {
        int j = idx - PREP_W2;
        int g = j >> 9, col = j & 511;
        const float* up = u + (size_t)g * GLOBAL_IN;
        float acc = b1[col];
        #pragma unroll 4
        for (int k = 0; k < GLOBAL_IN; ++k)
            acc += up[k] * W1[(size_t)(K1 + k) * HIDDEN + col];
        G[j] = acc;
    } else if (idx < PREP_Z) {
        cnt[idx - PREP_G] = 0;
    }
}

// ---------------- pass A: one-pass bucketed permutation ----------------
__global__ __launch_bounds__(256)
void fill_perm(const int* __restrict__ src, int* __restrict__ cnt,
               int* __restrict__ perm)
{
    int e = blockIdx.x * 256 + threadIdx.x;
    if (e < NE) {
        int s = src[e];
        int pos = atomicAdd(&cnt[s], 1);
        if (pos < MAXDEG) perm[(size_t)s * MAXDEG + pos] = e;
    }
}

// ---------------- fused: segmented mean + x copy -> comb row [NN, 320] bf16 --------
__global__ __launch_bounds__(256)
void seg_comb(const float* __restrict__ edge_attr,
              const int* __restrict__ perm,
              const int* __restrict__ cnt,
              const float* __restrict__ x,
              unsigned short* __restrict__ comb)
{
    int node = blockIdx.x * 4 + (threadIdx.x >> 6);
    if (node >= NN) return;
    int lane = threadIdx.x & 63;
    unsigned short* crow = comb + (size_t)node * K1;

    // x part: 64 lanes x float4 = 256 cols
    {
        const float4 v = *(const float4*)(x + (size_t)node * NODE_IN + lane * 4);
        us4 o = { f2bf(v.x), f2bf(v.y), f2bf(v.z), f2bf(v.w) };
        *(us4*)(crow + lane * 4) = o;
    }
    // edge mean: 4 edge-slots x 16 lanes, float4 per lane
    int c = cnt[node];
    int cc = c < MAXDEG ? c : MAXDEG;
    int g = lane >> 4;
    int f = (lane & 15) * 4;
    const int* pbase = perm + (size_t)node * MAXDEG;
    float4 acc = make_float4(0.f, 0.f, 0.f, 0.f);
    for (int i = g; i < cc; i += 4) {
        int e = pbase[i];
        const float4 v = *(const float4*)(edge_attr + (size_t)e * EDGE_OUT + f);
        acc.x += v.x; acc.y += v.y; acc.z += v.z; acc.w += v.w;
    }
    #pragma unroll
    for (int off = 16; off < 64; off <<= 1) {
        acc.x += __shfl_xor(acc.x, off, 64);
        acc.y += __shfl_xor(acc.y, off, 64);
        acc.z += __shfl_xor(acc.z, off, 64);
        acc.w += __shfl_xor(acc.w, off, 64);
    }
    if (g == 0) {
        float inv = 1.0f / fmaxf((float)c, 1.0f);
        us4 o = { f2bf(acc.x * inv), f2bf(acc.y * inv),
                  f2bf(acc.z * inv), f2bf(acc.w * inv) };
        *(us4*)(crow + NODE_IN + f) = o;
    }
}

// ---------------- fused MLP: out = relu(comb@W1T^T + G[batch]) @ W2T^T + b2 --------
// one block per 128 rows; 4 h-chunks of 128 cols; h never touches global memory
__global__ __launch_bounds__(256, 2)
void mlp_fused(const unsigned short* __restrict__ A,    // comb [M,320]
               const unsigned short* __restrict__ B1,   // W1T [512,320]
               const unsigned short* __restrict__ B2,   // W2T [256,512]
               const float* __restrict__ G,             // [64,512]
               const int* __restrict__ batch,           // [M]
               const float* __restrict__ bias2,         // [256]
               float* __restrict__ out, int M)
{
    __shared__ unsigned short lA[128 * 32];
    __shared__ unsigned short lB[128 * 32];
    __shared__ unsigned short lW2[256 * 32];
    __shared__ unsigned short hch[128 * HCH_LD];

    const int tid = threadIdx.x;
    const int w = tid >> 6, l = tid & 63;
    const int wr = w >> 1, wc = w & 1;
    const int m0 = blockIdx.x * 128;

    // lA/lB staging: 512 chunks of 16B, 2 per thread (m97 pattern)
    const int cA0 = w * 64 + l;
    const int cA1 = (w + 4) * 64 + l;
    const int rA0 = cA0 >> 2, kA0 = (cA0 & 3) * 8;
    const int rA1 = cA1 >> 2, kA1 = (cA1 & 3) * 8;
    int gr0 = m0 + rA0; if (gr0 >= M) gr0 = M - 1;
    int gr1 = m0 + rA1; if (gr1 >= M) gr1 = M - 1;
    const unsigned short* pA0 = A + (size_t)gr0 * K1 + kA0;
    const unsigned short* pA1 = A + (size_t)gr1 * K1 + kA1;

    // lW2 staging: 1024 chunks of 16B, 4 per thread; row = c>>2, koff = (c&3)*8
    const int cW0 = w * 64 + l;              // + i*256, i=0..3

    f32x4 acc2[4][8] = {};                    // out tile: wave = 64 rows x 128 cols

    const int lrow = wr * 64 + (l & 15);      // frag row base within tile
    const int lko  = (l >> 4) * 8;            // frag k offset

    for (int cc = 0; cc < 4; ++cc) {
        // ---- phase 1: acc1 = comb_tile @ W1T[cc*128 .. +128)^T ----
        f32x4 acc1[4][4] = {};
        const unsigned short* pB0 = B1 + (size_t)(cc * 128 + rA0) * K1 + kA0;
        const unsigned short* pB1b = B1 + (size_t)(cc * 128 + rA1) * K1 + kA1;
        for (int k0 = 0; k0 < K1; k0 += 32) {
            GLD_LDS(pA0 + k0, &lA[(size_t)cA0 * 8]);
            GLD_LDS(pA1 + k0, &lA[(size_t)cA1 * 8]);
            GLD_LDS(pB0 + k0, &lB[(size_t)cA0 * 8]);
            GLD_LDS(pB1b + k0, &lB[(size_t)cA1 * 8]);
            __syncthreads();
            bf16x8 af[4], bfr[4];
            #pragma unroll
            for (int m = 0; m < 4; ++m)
                af[m] = *(const bf16x8*)&lA[(wr * 64 + m * 16 + (l & 15)) * 32 + lko];
            #pragma unroll
            for (int n = 0; n < 4; ++n)
                bfr[n] = *(const bf16x8*)&lB[(wc * 64 + n * 16 + (l & 15)) * 32 + lko];
            #pragma unroll
            for (int m = 0; m < 4; ++m)
                #pragma unroll
                for (int n = 0; n < 4; ++n)
                    acc1[m][n] = __builtin_amdgcn_mfma_f32_16x16x32_bf16(af[m], bfr[n], acc1[m][n], 0, 0, 0);
            __syncthreads();
        }

        // ---- epilogue 1: hch = bf16(relu(acc1 + G[batch[row]][cc*128+col])) ----
        {
            const int colb = wc * 64 + (l & 15);         // local col base
            const int rowb = wr * 64 + ((l >> 4) << 2);  // local row base
            #pragma unroll
            for (int m = 0; m < 4; ++m) {
                #pragma unroll
                for (int j = 0; j < 4; ++j) {
                    int lr = rowb + m * 16 + j;
                    int grow = m0 + lr; if (grow >= M) grow = M - 1;
                    const float* gp = G + (size_t)batch[grow] * HIDDEN + cc * 128;
                    #pragma unroll
                    for (int n = 0; n < 4; ++n) {
                        int col = colb + n * 16;
                        float v = acc1[m][n][j] + gp[col];
                        hch[lr * HCH_LD + col] = f2bf(fmaxf(v, 0.0f));
                    }
                }
            }
        }

        // ---- phase 2: acc2 += hch[128x128] @ W2T[:, cc*128 .. +128)^T ----
        for (int k2 = 0; k2 < 128; k2 += 32) {
            #pragma unroll
            for (int i = 0; i < 4; ++i) {
                int c = cW0 + i * 256;
                int rw = c >> 2, ko = (c & 3) * 8;
                GLD_LDS(B2 + (size_t)rw * HIDDEN + cc * 128 + k2 + ko, &lW2[(size_t)c * 8]);
            }
            __syncthreads();   // also makes hch writes visible on first k2
            bf16x8 am[4];
            #pragma unroll
            for (int m = 0; m < 4; ++m)
                am[m] = *(const bf16x8*)&hch[(wr * 64 + m * 16 + (l & 15)) * HCH_LD + lko + k2];
            #pragma unroll
            for (int h = 0; h < 2; ++h) {
                bf16x8 bn[4];
                #pragma unroll
                for (int n = 0; n < 4; ++n)
                    bn[n] = *(const bf16x8*)&lW2[(wc * 128 + h * 64 + n * 16 + (l & 15)) * 32 + lko];
                #pragma unroll
                for (int m = 0; m < 4; ++m)
                    #pragma unroll
                    for (int n = 0; n < 4; ++n)
                        acc2[m][h * 4 + n] = __builtin_amdgcn_mfma_f32_16x16x32_bf16(am[m], bn[n], acc2[m][h * 4 + n], 0, 0, 0);
            }
            __syncthreads();
        }
    }

    // ---- final store: out[row][col] = acc2 + b2 ----
    const int cbase = wc * 128 + (l & 15);
    const int rbase = m0 + wr * 64 + ((l >> 4) << 2);
    #pragma unroll
    for (int m = 0; m < 4; ++m) {
        #pragma unroll
        for (int j = 0; j < 4; ++j) {
            int row = rbase + m * 16 + j;
            if (row < M) {
                #pragma unroll
                for (int nn = 0; nn < 8; ++nn) {
                    int col = cbase + nn * 16;
                    out[(size_t)row * NODE_OUT + col] = acc2[m][nn][j] + bias2[col];
                }
            }
        }
    }
}

extern "C" void kernel_launch(void* const* d_in, const int* in_sizes, int n_in,
                              void* d_out, int out_size, void* d_ws, size_t ws_size,
                              hipStream_t stream)
{
    const float* x         = (const float*)d_in[0];
    const int*   edge_idx  = (const int*)d_in[1];     // row 0 = src
    const float* edge_attr = (const float*)d_in[2];
    const float* u         = (const float*)d_in[3];
    const int*   batch     = (const int*)d_in[4];
    const float* W1        = (const float*)d_in[5];
    const float* b1        = (const float*)d_in[6];
    const float* W2        = (const float*)d_in[7];
    const float* b2        = (const float*)d_in[8];
    float* out = (float*)d_out;

    char* ws = (char*)d_ws;
    int*            cnt    = (int*)(ws);                       //    200,000 B
    int*            perm   = (int*)(ws + 200704);              // 12,800,000 B
    unsigned short* comb   = (unsigned short*)(ws + 13000704); // 32,000,000 B  [NN,320]
    unsigned short* W1T    = (unsigned short*)(ws + 45000704); //    327,680 B  [512,320]
    unsigned short* W2T    = (unsigned short*)(ws + 45328384); //    262,144 B  [256,512]
    float*          G      = (float*)(ws + 45590528);          //    131,072 B  [64,512]

    prep<<<(PREP_Z + 255) / 256, 256, 0, stream>>>(W1, W2, u, b1, W1T, W2T, G, cnt);

    fill_perm<<<(NE + 255) / 256, 256, 0, stream>>>(edge_idx, cnt, perm);

    seg_comb<<<(NN + 3) / 4, 256, 0, stream>>>(edge_attr, perm, cnt, x, comb);

    mlp_fused<<<(NN + 127) / 128, 256, 0, stream>>>(
        comb, W1T, W2T, G, batch, b2, out, NN);
}

// Round 8
// 221.289 us; speedup vs baseline: 1.2633x; 1.2633x over previous
//
#include <hip/hip_runtime.h>
#include <hip/hip_bf16.h>
#include <stdint.h>

#define NN 50000
#define NE 800000
#define NODE_IN 256
#define EDGE_OUT 64
#define GLOBAL_IN 128
#define NODE_OUT 256
#define HIDDEN 512
#define K1 320          // NODE_IN + EDGE_OUT (u-part folded into per-graph bias G)
#define N_GRAPHS 64
#define MAXDEG 64       // Poisson(16) tail: P(deg>64) ~ 1e-18 per node; writes guarded

typedef __attribute__((ext_vector_type(8))) short bf16x8;
typedef __attribute__((ext_vector_type(4))) float f32x4;
typedef __attribute__((ext_vector_type(4))) unsigned short us4;

__device__ __forceinline__ unsigned short f2bf(float x) {
    union { float f; unsigned int u; } c; c.f = x;
    unsigned int u = c.u;
    unsigned int r = (u + 0x7FFFu + ((u >> 16) & 1u)) >> 16;
    return (unsigned short)r;
}

#define GLD_LDS(gp, lp) __builtin_amdgcn_global_load_lds( \
    (const __attribute__((address_space(1))) unsigned int*)(gp), \
    (__attribute__((address_space(3))) unsigned int*)(lp), 16, 0, 0)

// ---------------- prep: W1T (K<320), W2T, G = u@W1_u + b1, zero cnt ----------------
#define PREP_W1 (HIDDEN * K1)                 // 163840
#define PREP_W2 (PREP_W1 + NODE_OUT * HIDDEN) // +131072 = 294912
#define PREP_G  (PREP_W2 + N_GRAPHS * HIDDEN) // +32768  = 327680
#define PREP_Z  (PREP_G + NN)                 // +50000  = 377680
__global__ __launch_bounds__(256)
void prep(const float* __restrict__ W1, const float* __restrict__ W2,
          const float* __restrict__ u, const float* __restrict__ b1,
          unsigned short* __restrict__ W1T, unsigned short* __restrict__ W2T,
          float* __restrict__ G, int* __restrict__ cnt)
{
    int idx = blockIdx.x * 256 + threadIdx.x;
    if (idx < PREP_W1) {
        int n = idx / K1, k = idx - n * K1;
        W1T[idx] = f2bf(W1[(size_t)k * HIDDEN + n]);          // W1T[n][k], k<320
    } else if (idx < PREP_W2) {
        int j = idx - PREP_W1;
        int n = j / HIDDEN, k = j - n * HIDDEN;
        W2T[j] = f2bf(W2[(size_t)k * NODE_OUT + n]);
    } else if (idx < PREP_G) {
        int j = idx - PREP_W2;
        int g = j >> 9, col = j & 511;
        const float* up = u + (size_t)g * GLOBAL_IN;
        float acc = b1[col];
        #pragma unroll 4
        for (int k = 0; k < GLOBAL_IN; ++k)
            acc += up[k] * W1[(size_t)(K1 + k) * HIDDEN + col];
        G[j] = acc;
    } else if (idx < PREP_Z) {
        cnt[idx - PREP_G] = 0;
    }
}

// ---------------- pass A: one-pass bucketed permutation ----------------
__global__ __launch_bounds__(256)
void fill_perm(const int* __restrict__ src, int* __restrict__ cnt,
               int* __restrict__ perm)
{
    int e = blockIdx.x * 256 + threadIdx.x;
    if (e < NE) {
        int s = src[e];
        int pos = atomicAdd(&cnt[s], 1);
        if (pos < MAXDEG) perm[(size_t)s * MAXDEG + pos] = e;
    }
}

// ---------------- fused: segmented mean + x copy -> comb row [NN, 320] bf16 --------
__global__ __launch_bounds__(256)
void seg_comb(const float* __restrict__ edge_attr,
              const int* __restrict__ perm,
              const int* __restrict__ cnt,
              const float* __restrict__ x,
              unsigned short* __restrict__ comb)
{
    int node = blockIdx.x * 4 + (threadIdx.x >> 6);
    if (node >= NN) return;
    int lane = threadIdx.x & 63;
    unsigned short* crow = comb + (size_t)node * K1;

    // x part: 64 lanes x float4 = 256 cols
    {
        const float4 v = *(const float4*)(x + (size_t)node * NODE_IN + lane * 4);
        us4 o = { f2bf(v.x), f2bf(v.y), f2bf(v.z), f2bf(v.w) };
        *(us4*)(crow + lane * 4) = o;
    }
    // edge mean: 4 edge-slots x 16 lanes, float4 per lane
    int c = cnt[node];
    int cc = c < MAXDEG ? c : MAXDEG;
    int g = lane >> 4;
    int f = (lane & 15) * 4;
    const int* pbase = perm + (size_t)node * MAXDEG;
    float4 acc = make_float4(0.f, 0.f, 0.f, 0.f);
    for (int i = g; i < cc; i += 4) {
        int e = pbase[i];
        const float4 v = *(const float4*)(edge_attr + (size_t)e * EDGE_OUT + f);
        acc.x += v.x; acc.y += v.y; acc.z += v.z; acc.w += v.w;
    }
    #pragma unroll
    for (int off = 16; off < 64; off <<= 1) {
        acc.x += __shfl_xor(acc.x, off, 64);
        acc.y += __shfl_xor(acc.y, off, 64);
        acc.z += __shfl_xor(acc.z, off, 64);
        acc.w += __shfl_xor(acc.w, off, 64);
    }
    if (g == 0) {
        float inv = 1.0f / fmaxf((float)c, 1.0f);
        us4 o = { f2bf(acc.x * inv), f2bf(acc.y * inv),
                  f2bf(acc.z * inv), f2bf(acc.w * inv) };
        *(us4*)(crow + NODE_IN + f) = o;
    }
}

// ---------------- bf16 GEMM, C[M,N] = A[M,K] * B[N,K]^T, m97 + T2 + T1 ----------------
// LDS layout: tile[row][col16] where data for (row, k16) lives at col16 = k16 ^ (row&3)
//   (16-byte granules; inverse-swizzled global source + swizzled ds_read, rule #21)
// EPI=0: bias = G[batch[row]][col] (HIDDEN-wide rows), relu -> bf16 out
// EPI=1: bias = b[col], plain -> f32 out
template<int EPI>
__global__ __launch_bounds__(256)
void gemm_bt_128(const unsigned short* __restrict__ A,
                 const unsigned short* __restrict__ B,
                 const float* __restrict__ bias,
                 const int* __restrict__ batch,
                 void* __restrict__ Cv,
                 int M, int N, int K)
{
    __shared__ unsigned short lA[128 * 32];
    __shared__ unsigned short lB[128 * 32];
    const int tid = threadIdx.x;
    const int w = tid >> 6, l = tid & 63;

    // ---- T1: bijective XCD swizzle (m204): same-y panels land on one XCD ----
    const int nwg  = gridDim.x * gridDim.y;
    const int orig = blockIdx.x + gridDim.x * blockIdx.y;
    const int q = nwg >> 3, r = nwg & 7;
    const int xcd = orig & 7, sidx = orig >> 3;
    const int wg = (xcd < r ? xcd * (q + 1) : r * (q + 1) + (xcd - r) * q) + sidx;
    const int m0 = (wg / gridDim.x) * 128;
    const int n0 = (wg % gridDim.x) * 128;

    const int wr = w >> 1, wc = w & 1;

    f32x4 acc[4][4] = {};

    // staging: chunk c (16B) -> LDS byte c*16 (linear, GLD_LDS-compatible);
    // row = c>>2; source k-granule = (c&3) ^ (row&3)  [inverse swizzle]
    const int cA0 = w * 64 + l;          // chunks 0..255  (rows 0..63)
    const int cA1 = cA0 + 256;           // chunks 256..511 (rows 64..127)
    const int rA0 = cA0 >> 2, kA0 = (((cA0 & 3) ^ (rA0 & 3)) * 8);
    const int rA1 = cA1 >> 2, kA1 = (((cA1 & 3) ^ (rA1 & 3)) * 8);
    int gr0 = m0 + rA0; if (gr0 >= M) gr0 = M - 1;   // clamp (stores guarded)
    int gr1 = m0 + rA1; if (gr1 >= M) gr1 = M - 1;
    const unsigned short* pA0 = A + (size_t)gr0 * K + kA0;
    const unsigned short* pA1 = A + (size_t)gr1 * K + kA1;
    const unsigned short* pB0 = B + (size_t)(n0 + rA0) * K + kA0;
    const unsigned short* pB1 = B + (size_t)(n0 + rA1) * K + kA1;

    const int lko = (l >> 4) * 8;        // k-offset (shorts) this lane reads

    for (int k0 = 0; k0 < K; k0 += 32) {
        GLD_LDS(pA0 + k0, &lA[(size_t)cA0 * 8]);
        GLD_LDS(pA1 + k0, &lA[(size_t)cA1 * 8]);
        GLD_LDS(pB0 + k0, &lB[(size_t)cA0 * 8]);
        GLD_LDS(pB1 + k0, &lB[(size_t)cA1 * 8]);
        __syncthreads();

        bf16x8 af[4], bfr[4];
        #pragma unroll
        for (int m = 0; m < 4; ++m) {
            int ar = wr * 64 + m * 16 + (l & 15);
            af[m] = *(const bf16x8*)&lA[ar * 32 + (lko ^ ((ar & 3) << 3))];
        }
        #pragma unroll
        for (int n = 0; n < 4; ++n) {
            int br = wc * 64 + n * 16 + (l & 15);
            bfr[n] = *(const bf16x8*)&lB[br * 32 + (lko ^ ((br & 3) << 3))];
        }

        #pragma unroll
        for (int m = 0; m < 4; ++m)
            #pragma unroll
            for (int n = 0; n < 4; ++n)
                acc[m][n] = __builtin_amdgcn_mfma_f32_16x16x32_bf16(af[m], bfr[n], acc[m][n], 0, 0, 0);

        __syncthreads();
    }

    const int cbase = n0 + wc * 64 + (l & 15);
    const int rbase = m0 + wr * 64 + ((l >> 4) << 2);
    if (EPI == 0) {
        unsigned short* C = (unsigned short*)Cv;
        #pragma unroll
        for (int m = 0; m < 4; ++m) {
            #pragma unroll
            for (int j = 0; j < 4; ++j) {
                int row = rbase + m * 16 + j;
                if (row < M) {
                    const float* grow = bias + (size_t)batch[row] * HIDDEN;
                    #pragma unroll
                    for (int n = 0; n < 4; ++n) {
                        int c = cbase + n * 16;
                        float v = acc[m][n][j] + grow[c];
                        v = fmaxf(v, 0.0f);
                        C[(size_t)row * N + c] = f2bf(v);
                    }
                }
            }
        }
    } else {
        float* C = (float*)Cv;
        #pragma unroll
        for (int m = 0; m < 4; ++m) {
            #pragma unroll
            for (int j = 0; j < 4; ++j) {
                int row = rbase + m * 16 + j;
                if (row < M) {
                    #pragma unroll
                    for (int n = 0; n < 4; ++n) {
                        int c = cbase + n * 16;
                        C[(size_t)row * N + c] = acc[m][n][j] + bias[c];
                    }
                }
            }
        }
    }
}

extern "C" void kernel_launch(void* const* d_in, const int* in_sizes, int n_in,
                              void* d_out, int out_size, void* d_ws, size_t ws_size,
                              hipStream_t stream)
{
    const float* x         = (const float*)d_in[0];
    const int*   edge_idx  = (const int*)d_in[1];     // row 0 = src
    const float* edge_attr = (const float*)d_in[2];
    const float* u         = (const float*)d_in[3];
    const int*   batch     = (const int*)d_in[4];
    const float* W1        = (const float*)d_in[5];
    const float* b1        = (const float*)d_in[6];
    const float* W2        = (const float*)d_in[7];
    const float* b2        = (const float*)d_in[8];
    float* out = (float*)d_out;

    char* ws = (char*)d_ws;
    int*            cnt    = (int*)(ws);                       //    200,000 B
    int*            perm   = (int*)(ws + 200704);              // 12,800,000 B
    unsigned short* comb   = (unsigned short*)(ws + 13000704); // 32,000,000 B  [NN,320]
    unsigned short* W1T    = (unsigned short*)(ws + 45000704); //    327,680 B  [512,320]
    unsigned short* W2T    = (unsigned short*)(ws + 45328384); //    262,144 B  [256,512]
    float*          G      = (float*)(ws + 45590528);          //    131,072 B  [64,512]
    unsigned short* h      = (unsigned short*)(ws + 45721600); // 51,200,000 B  (end ~97 MB)

    prep<<<(PREP_Z + 255) / 256, 256, 0, stream>>>(W1, W2, u, b1, W1T, W2T, G, cnt);

    fill_perm<<<(NE + 255) / 256, 256, 0, stream>>>(edge_idx, cnt, perm);

    seg_comb<<<(NN + 3) / 4, 256, 0, stream>>>(edge_attr, perm, cnt, x, comb);

    gemm_bt_128<0><<<dim3(HIDDEN / 128, (NN + 127) / 128), 256, 0, stream>>>(
        comb, W1T, G, batch, h, NN, HIDDEN, K1);
    gemm_bt_128<1><<<dim3(NODE_OUT / 128, (NN + 127) / 128), 256, 0, stream>>>(
        h, W2T, b2, nullptr, out, NN, NODE_OUT, HIDDEN);
}

// Round 9
// 213.288 us; speedup vs baseline: 1.3107x; 1.0375x over previous
//
#include <hip/hip_runtime.h>
#include <hip/hip_bf16.h>
#include <stdint.h>

#define NN 50000
#define NE 800000
#define NODE_IN 256
#define EDGE_OUT 64
#define GLOBAL_IN 128
#define NODE_OUT 256
#define HIDDEN 512
#define K1 320          // NODE_IN + EDGE_OUT (u-part folded into per-graph bias G)
#define N_GRAPHS 64
#define MAXDEG 64       // Poisson(16) tail: P(deg>64) ~ 1e-18 per node; writes guarded

typedef __attribute__((ext_vector_type(8))) short bf16x8;
typedef __attribute__((ext_vector_type(4))) float f32x4;
typedef __attribute__((ext_vector_type(4))) unsigned short us4;

__device__ __forceinline__ unsigned short f2bf(float x) {
    union { float f; unsigned int u; } c; c.f = x;
    unsigned int u = c.u;
    unsigned int r = (u + 0x7FFFu + ((u >> 16) & 1u)) >> 16;
    return (unsigned short)r;
}

#define GLD_LDS(gp, lp) __builtin_amdgcn_global_load_lds( \
    (const __attribute__((address_space(1))) unsigned int*)(gp), \
    (__attribute__((address_space(3))) unsigned int*)(lp), 16, 0, 0)

// ---------------- prep: W1T (K<320), W2T, G = u@W1_u + b1, zero cnt ----------------
#define PREP_W1 (HIDDEN * K1)                 // 163840
#define PREP_W2 (PREP_W1 + NODE_OUT * HIDDEN) // +131072 = 294912
#define PREP_G  (PREP_W2 + N_GRAPHS * HIDDEN) // +32768  = 327680
#define PREP_Z  (PREP_G + NN)                 // +50000  = 377680
__global__ __launch_bounds__(256)
void prep(const float* __restrict__ W1, const float* __restrict__ W2,
          const float* __restrict__ u, const float* __restrict__ b1,
          unsigned short* __restrict__ W1T, unsigned short* __restrict__ W2T,
          float* __restrict__ G, int* __restrict__ cnt)
{
    int idx = blockIdx.x * 256 + threadIdx.x;
    if (idx < PREP_W1) {
        int n = idx / K1, k = idx - n * K1;
        W1T[idx] = f2bf(W1[(size_t)k * HIDDEN + n]);          // W1T[n][k], k<320
    } else if (idx < PREP_W2) {
        int j = idx - PREP_W1;
        int n = j / HIDDEN, k = j - n * HIDDEN;
        W2T[j] = f2bf(W2[(size_t)k * NODE_OUT + n]);
    } else if (idx < PREP_G) {
        int j = idx - PREP_W2;
        int g = j >> 9, col = j & 511;
        const float* up = u + (size_t)g * GLOBAL_IN;
        float acc = b1[col];
        #pragma unroll 4
        for (int k = 0; k < GLOBAL_IN; ++k)
            acc += up[k] * W1[(size_t)(K1 + k) * HIDDEN + col];
        G[j] = acc;
    } else if (idx < PREP_Z) {
        cnt[idx - PREP_G] = 0;
    }
}

// ---------------- pass A: one-pass bucketed permutation ----------------
__global__ __launch_bounds__(256)
void fill_perm(const int* __restrict__ src, int* __restrict__ cnt,
               int* __restrict__ perm)
{
    int e = blockIdx.x * 256 + threadIdx.x;
    if (e < NE) {
        int s = src[e];
        int pos = atomicAdd(&cnt[s], 1);
        if (pos < MAXDEG) perm[(size_t)s * MAXDEG + pos] = e;
    }
}

// ---------------- fused: segmented mean + x copy -> comb row [NN, 320] bf16 --------
__global__ __launch_bounds__(256)
void seg_comb(const float* __restrict__ edge_attr,
              const int* __restrict__ perm,
              const int* __restrict__ cnt,
              const float* __restrict__ x,
              unsigned short* __restrict__ comb)
{
    int node = blockIdx.x * 4 + (threadIdx.x >> 6);
    if (node >= NN) return;
    int lane = threadIdx.x & 63;
    unsigned short* crow = comb + (size_t)node * K1;

    // x part: 64 lanes x float4 = 256 cols
    {
        const float4 v = *(const float4*)(x + (size_t)node * NODE_IN + lane * 4);
        us4 o = { f2bf(v.x), f2bf(v.y), f2bf(v.z), f2bf(v.w) };
        *(us4*)(crow + lane * 4) = o;
    }
    // edge mean: 4 edge-slots x 16 lanes, float4 per lane; 2x unrolled (8 loads in flight)
    int c = cnt[node];
    int cc = c < MAXDEG ? c : MAXDEG;
    int g = lane >> 4;
    int f = (lane & 15) * 4;
    const int* pbase = perm + (size_t)node * MAXDEG;
    float4 a0 = make_float4(0.f, 0.f, 0.f, 0.f);
    float4 a1 = make_float4(0.f, 0.f, 0.f, 0.f);
    int i = g;
    for (; i + 4 < cc; i += 8) {
        int e0 = pbase[i];
        int e1 = pbase[i + 4];
        const float4 v0 = *(const float4*)(edge_attr + (size_t)e0 * EDGE_OUT + f);
        const float4 v1 = *(const float4*)(edge_attr + (size_t)e1 * EDGE_OUT + f);
        a0.x += v0.x; a0.y += v0.y; a0.z += v0.z; a0.w += v0.w;
        a1.x += v1.x; a1.y += v1.y; a1.z += v1.z; a1.w += v1.w;
    }
    if (i < cc) {
        int e0 = pbase[i];
        const float4 v0 = *(const float4*)(edge_attr + (size_t)e0 * EDGE_OUT + f);
        a0.x += v0.x; a0.y += v0.y; a0.z += v0.z; a0.w += v0.w;
    }
    float4 acc = make_float4(a0.x + a1.x, a0.y + a1.y, a0.z + a1.z, a0.w + a1.w);
    #pragma unroll
    for (int off = 16; off < 64; off <<= 1) {
        acc.x += __shfl_xor(acc.x, off, 64);
        acc.y += __shfl_xor(acc.y, off, 64);
        acc.z += __shfl_xor(acc.z, off, 64);
        acc.w += __shfl_xor(acc.w, off, 64);
    }
    if (g == 0) {
        float inv = 1.0f / fmaxf((float)c, 1.0f);
        us4 o = { f2bf(acc.x * inv), f2bf(acc.y * inv),
                  f2bf(acc.z * inv), f2bf(acc.w * inv) };
        *(us4*)(crow + NODE_IN + f) = o;
    }
}

// ---------------- bf16 GEMM, C[M,N] = A[M,K] * B[N,K]^T, BK=64 + T1 + T2 ------------
// LDS tile [128 rows][8 granules of 16B]; granule at (row,gpos) holds k-granule
// kt = gpos ^ (row&7)  (involution; staged via inverse-swizzled global source,
// GLD_LDS dest linear — rule #21). 128B row stride -> swizzled 16-lane column
// read covers all 32 banks at 2 lanes/bank = conflict-free (m136).
// EPI=0: bias = G[batch[row]][col] (HIDDEN-wide rows), relu -> bf16 out
// EPI=1: bias = b[col], plain -> f32 out
template<int EPI>
__global__ __launch_bounds__(256)
void gemm_bt_128(const unsigned short* __restrict__ A,
                 const unsigned short* __restrict__ B,
                 const float* __restrict__ bias,
                 const int* __restrict__ batch,
                 void* __restrict__ Cv,
                 int M, int N, int K)
{
    __shared__ unsigned short lA[128 * 64];
    __shared__ unsigned short lB[128 * 64];
    const int tid = threadIdx.x;
    const int w = tid >> 6, l = tid & 63;

    // ---- T1: bijective XCD swizzle (m204): same-y panels land on one XCD ----
    const int nwg  = gridDim.x * gridDim.y;
    const int orig = blockIdx.x + gridDim.x * blockIdx.y;
    const int q = nwg >> 3, r = nwg & 7;
    const int xcd = orig & 7, sidx = orig >> 3;
    const int wg = (xcd < r ? xcd * (q + 1) : r * (q + 1) + (xcd - r) * q) + sidx;
    const int m0 = (wg / gridDim.x) * 128;
    const int n0 = (wg % gridDim.x) * 128;

    const int wr = w >> 1, wc = w & 1;

    f32x4 acc[4][4] = {};

    // staging: 1024 granules (16B) per matrix, 4 per thread; chunk c = tid + i*256
    // row = c>>3, gpos = c&7, source k-granule = gpos ^ (row&7)
    const unsigned short* pAs[4];
    const unsigned short* pBs[4];
    #pragma unroll
    for (int i = 0; i < 4; ++i) {
        int c = tid + i * 256;
        int row = c >> 3;
        int kg = ((c & 7) ^ (row & 7)) * 8;          // shorts
        int gr = m0 + row; if (gr >= M) gr = M - 1;  // clamp (stores guarded)
        pAs[i] = A + (size_t)gr * K + kg;
        pBs[i] = B + (size_t)(n0 + row) * K + kg;
    }

    for (int k0 = 0; k0 < K; k0 += 64) {
        #pragma unroll
        for (int i = 0; i < 4; ++i)
            GLD_LDS(pAs[i] + k0, &lA[(size_t)(tid + i * 256) * 8]);
        #pragma unroll
        for (int i = 0; i < 4; ++i)
            GLD_LDS(pBs[i] + k0, &lB[(size_t)(tid + i * 256) * 8]);
        __syncthreads();

        #pragma unroll
        for (int kk = 0; kk < 2; ++kk) {
            bf16x8 af[4], bfr[4];
            #pragma unroll
            for (int m = 0; m < 4; ++m) {
                int ar = wr * 64 + m * 16 + (l & 15);
                int gran = (kk * 4 + (l >> 4)) ^ (ar & 7);
                af[m] = *(const bf16x8*)&lA[ar * 64 + gran * 8];
            }
            #pragma unroll
            for (int n = 0; n < 4; ++n) {
                int br = wc * 64 + n * 16 + (l & 15);
                int gran = (kk * 4 + (l >> 4)) ^ (br & 7);
                bfr[n] = *(const bf16x8*)&lB[br * 64 + gran * 8];
            }
            #pragma unroll
            for (int m = 0; m < 4; ++m)
                #pragma unroll
                for (int n = 0; n < 4; ++n)
                    acc[m][n] = __builtin_amdgcn_mfma_f32_16x16x32_bf16(af[m], bfr[n], acc[m][n], 0, 0, 0);
        }
        __syncthreads();
    }

    const int cbase = n0 + wc * 64 + (l & 15);
    const int rbase = m0 + wr * 64 + ((l >> 4) << 2);
    if (EPI == 0) {
        unsigned short* C = (unsigned short*)Cv;
        #pragma unroll
        for (int m = 0; m < 4; ++m) {
            #pragma unroll
            for (int j = 0; j < 4; ++j) {
                int row = rbase + m * 16 + j;
                if (row < M) {
                    const float* grow = bias + (size_t)batch[row] * HIDDEN;
                    #pragma unroll
                    for (int n = 0; n < 4; ++n) {
                        int c = cbase + n * 16;
                        float v = acc[m][n][j] + grow[c];
                        v = fmaxf(v, 0.0f);
                        C[(size_t)row * N + c] = f2bf(v);
                    }
                }
            }
        }
    } else {
        float* C = (float*)Cv;
        #pragma unroll
        for (int m = 0; m < 4; ++m) {
            #pragma unroll
            for (int j = 0; j < 4; ++j) {
                int row = rbase + m * 16 + j;
                if (row < M) {
                    #pragma unroll
                    for (int n = 0; n < 4; ++n) {
                        int c = cbase + n * 16;
                        C[(size_t)row * N + c] = acc[m][n][j] + bias[c];
                    }
                }
            }
        }
    }
}

extern "C" void kernel_launch(void* const* d_in, const int* in_sizes, int n_in,
                              void* d_out, int out_size, void* d_ws, size_t ws_size,
                              hipStream_t stream)
{
    const float* x         = (const float*)d_in[0];
    const int*   edge_idx  = (const int*)d_in[1];     // row 0 = src
    const float* edge_attr = (const float*)d_in[2];
    const float* u         = (const float*)d_in[3];
    const int*   batch     = (const int*)d_in[4];
    const float* W1        = (const float*)d_in[5];
    const float* b1        = (const float*)d_in[6];
    const float* W2        = (const float*)d_in[7];
    const float* b2        = (const float*)d_in[8];
    float* out = (float*)d_out;

    char* ws = (char*)d_ws;
    int*            cnt    = (int*)(ws);                       //    200,000 B
    int*            perm   = (int*)(ws + 200704);              // 12,800,000 B
    unsigned short* comb   = (unsigned short*)(ws + 13000704); // 32,000,000 B  [NN,320]
    unsigned short* W1T    = (unsigned short*)(ws + 45000704); //    327,680 B  [512,320]
    unsigned short* W2T    = (unsigned short*)(ws + 45328384); //    262,144 B  [256,512]
    float*          G      = (float*)(ws + 45590528);          //    131,072 B  [64,512]
    unsigned short* h      = (unsigned short*)(ws + 45721600); // 51,200,000 B  (end ~97 MB)

    prep<<<(PREP_Z + 255) / 256, 256, 0, stream>>>(W1, W2, u, b1, W1T, W2T, G, cnt);

    fill_perm<<<(NE + 255) / 256, 256, 0, stream>>>(edge_idx, cnt, perm);

    seg_comb<<<(NN + 3) / 4, 256, 0, stream>>>(edge_attr, perm, cnt, x, comb);

    gemm_bt_128<0><<<dim3(HIDDEN / 128, (NN + 127) / 128), 256, 0, stream>>>(
        comb, W1T, G, batch, h, NN, HIDDEN, K1);
    gemm_bt_128<1><<<dim3(NODE_OUT / 128, (NN + 127) / 128), 256, 0, stream>>>(
        h, W2T, b2, nullptr, out, NN, NODE_OUT, HIDDEN);
}

// Round 12
// 206.429 us; speedup vs baseline: 1.3543x; 1.0332x over previous
//
#include <hip/hip_runtime.h>
#include <hip/hip_bf16.h>
#include <stdint.h>

#define NN 50000
#define NE 800000
#define NODE_IN 256
#define EDGE_OUT 64
#define GLOBAL_IN 128
#define NODE_OUT 256
#define HIDDEN 512
#define K1 320          // NODE_IN + EDGE_OUT (u-part folded into per-graph bias G)
#define N_GRAPHS 64
#define MAXDEG 64       // Poisson(16) tail: P(deg>64) ~ 1e-18 per node; writes guarded

typedef __attribute__((ext_vector_type(8))) short bf16x8;
typedef __attribute__((ext_vector_type(4))) float f32x4;
typedef __attribute__((ext_vector_type(4))) unsigned short us4;

__device__ __forceinline__ unsigned short f2bf(float x) {
    union { float f; unsigned int u; } c; c.f = x;
    unsigned int u = c.u;
    unsigned int r = (u + 0x7FFFu + ((u >> 16) & 1u)) >> 16;
    return (unsigned short)r;
}

#define GLD_LDS(gp, lp) __builtin_amdgcn_global_load_lds( \
    (const __attribute__((address_space(1))) unsigned int*)(gp), \
    (__attribute__((address_space(3))) unsigned int*)(lp), 16, 0, 0)

// ---------------- prep: W1T (K<320), W2T, G = u@W1_u + b1, zero cnt ----------------
#define PREP_W1 (HIDDEN * K1)                 // 163840
#define PREP_W2 (PREP_W1 + NODE_OUT * HIDDEN) // +131072 = 294912
#define PREP_G  (PREP_W2 + N_GRAPHS * HIDDEN) // +32768  = 327680
#define PREP_Z  (PREP_G + NN)                 // +50000  = 377680
__global__ __launch_bounds__(256)
void prep(const float* __restrict__ W1, const float* __restrict__ W2,
          const float* __restrict__ u, const float* __restrict__ b1,
          unsigned short* __restrict__ W1T, unsigned short* __restrict__ W2T,
          float* __restrict__ G, int* __restrict__ cnt)
{
    int idx = blockIdx.x * 256 + threadIdx.x;
    if (idx < PREP_W1) {
        int n = idx / K1, k = idx - n * K1;
        W1T[idx] = f2bf(W1[(size_t)k * HIDDEN + n]);          // W1T[n][k], k<320
    } else if (idx < PREP_W2) {
        int j = idx - PREP_W1;
        int n = j / HIDDEN, k = j - n * HIDDEN;
        W2T[j] = f2bf(W2[(size_t)k * NODE_OUT + n]);
    } else if (idx < PREP_G) {
        int j = idx - PREP_W2;
        int g = j >> 9, col = j & 511;
        const float* up = u + (size_t)g * GLOBAL_IN;
        float acc = b1[col];
        #pragma unroll 4
        for (int k = 0; k < GLOBAL_IN; ++k)
            acc += up[k] * W1[(size_t)(K1 + k) * HIDDEN + col];
        G[j] = acc;
    } else if (idx < PREP_Z) {
        cnt[idx - PREP_G] = 0;
    }
}

// ---------------- pass A: bucketed perm fill + x->comb copy (grid-stride) ----------
__global__ __launch_bounds__(256)
void fillx(const int* __restrict__ src, int* __restrict__ cnt,
           int* __restrict__ perm, const float* __restrict__ x,
           unsigned short* __restrict__ comb)
{
    const int gs = gridDim.x * 256;
    for (int e = blockIdx.x * 256 + threadIdx.x; e < NE; e += gs) {
        int s = src[e];
        int pos = atomicAdd(&cnt[s], 1);
        if (pos < MAXDEG) perm[(size_t)s * MAXDEG + pos] = e;
    }
    for (int q = blockIdx.x * 256 + threadIdx.x; q < NN * 64; q += gs) {
        int node = q >> 6, lane = q & 63;
        const float4 v = *(const float4*)(x + (size_t)node * NODE_IN + lane * 4);
        us4 o = { f2bf(v.x), f2bf(v.y), f2bf(v.z), f2bf(v.w) };
        *(us4*)(comb + (size_t)node * K1 + lane * 4) = o;
    }
}

// ---------------- pass B: segmented mean -> comb[:,256:320] (bf16) ----------------
// wave = 1 node; bucket preloaded coalesced; UNIFORM trip count so every
// __shfl source lane is active (round-10/11 bug: divergent groups made
// shfl read exec-masked-off lanes -> undefined). Loads predicated on i<cc.
__global__ __launch_bounds__(256)
void seg(const float* __restrict__ edge_attr, const int* __restrict__ perm,
         const int* __restrict__ cnt, unsigned short* __restrict__ comb)
{
    int node = blockIdx.x * 4 + (threadIdx.x >> 6);
    if (node >= NN) return;                  // NN%4==0: whole waves only
    int lane = threadIdx.x & 63;
    int g = lane >> 4, f = (lane & 15) * 4;
    int c = cnt[node];
    int cc = c < MAXDEG ? c : MAXDEG;        // wave-uniform
    const int* pbase = perm + (size_t)node * MAXDEG;
    int eperm = pbase[lane];                 // one coalesced read = whole bucket
    float4 a0 = make_float4(0.f, 0.f, 0.f, 0.f);
    float4 a1 = make_float4(0.f, 0.f, 0.f, 0.f);
    const int nb = (cc + 7) >> 3;            // uniform loop count for all lanes
    for (int kb = 0; kb < nb; ++kb) {
        int i0 = (kb << 3) + g;              // <= 59
        int i1 = i0 + 4;                     // <= 63
        int e0 = __shfl(eperm, i0, 64);      // all lanes active -> defined
        int e1 = __shfl(eperm, i1, 64);
        if (i0 < cc) {
            const float4 v0 = *(const float4*)(edge_attr + (size_t)e0 * EDGE_OUT + f);
            a0.x += v0.x; a0.y += v0.y; a0.z += v0.z; a0.w += v0.w;
        }
        if (i1 < cc) {
            const float4 v1 = *(const float4*)(edge_attr + (size_t)e1 * EDGE_OUT + f);
            a1.x += v1.x; a1.y += v1.y; a1.z += v1.z; a1.w += v1.w;
        }
    }
    float4 acc = make_float4(a0.x + a1.x, a0.y + a1.y, a0.z + a1.z, a0.w + a1.w);
    #pragma unroll
    for (int off = 16; off < 64; off <<= 1) {
        acc.x += __shfl_xor(acc.x, off, 64);
        acc.y += __shfl_xor(acc.y, off, 64);
        acc.z += __shfl_xor(acc.z, off, 64);
        acc.w += __shfl_xor(acc.w, off, 64);
    }
    if (g == 0) {
        float inv = 1.0f / fmaxf((float)c, 1.0f);
        us4 o = { f2bf(acc.x * inv), f2bf(acc.y * inv),
                  f2bf(acc.z * inv), f2bf(acc.w * inv) };
        *(us4*)(comb + (size_t)node * K1 + NODE_IN + f) = o;
    }
}

// ---------------- bf16 GEMM, C[M,N] = A[M,K] * B[N,K]^T, BK=64 + T1 + T2 ------------
// (round-9 verified) LDS tile [128 rows][8 granules of 16B]; granule (row,gpos)
// holds k-granule kt = gpos ^ (row&7); staged via inverse-swizzled global source.
// EPI=0: bias = G[batch[row]][col], relu -> bf16 out ; EPI=1: bias=b[col] -> f32 out
template<int EPI>
__global__ __launch_bounds__(256)
void gemm_bt_128(const unsigned short* __restrict__ A,
                 const unsigned short* __restrict__ B,
                 const float* __restrict__ bias,
                 const int* __restrict__ batch,
                 void* __restrict__ Cv,
                 int M, int N, int K)
{
    __shared__ unsigned short lA[128 * 64];
    __shared__ unsigned short lB[128 * 64];
    const int tid = threadIdx.x;
    const int w = tid >> 6, l = tid & 63;

    // ---- T1: bijective XCD swizzle (m204): same-y panels land on one XCD ----
    const int nwg  = gridDim.x * gridDim.y;
    const int orig = blockIdx.x + gridDim.x * blockIdx.y;
    const int q = nwg >> 3, r = nwg & 7;
    const int xcd = orig & 7, sidx = orig >> 3;
    const int wg = (xcd < r ? xcd * (q + 1) : r * (q + 1) + (xcd - r) * q) + sidx;
    const int m0 = (wg / gridDim.x) * 128;
    const int n0 = (wg % gridDim.x) * 128;

    const int wr = w >> 1, wc = w & 1;

    f32x4 acc[4][4] = {};

    const unsigned short* pAs[4];
    const unsigned short* pBs[4];
    #pragma unroll
    for (int i = 0; i < 4; ++i) {
        int c = tid + i * 256;
        int row = c >> 3;
        int kg = ((c & 7) ^ (row & 7)) * 8;          // inverse-swizzled source granule
        int gr = m0 + row; if (gr >= M) gr = M - 1;  // clamp (stores guarded)
        pAs[i] = A + (size_t)gr * K + kg;
        pBs[i] = B + (size_t)(n0 + row) * K + kg;
    }

    for (int k0 = 0; k0 < K; k0 += 64) {
        #pragma unroll
        for (int i = 0; i < 4; ++i)
            GLD_LDS(pAs[i] + k0, &lA[(size_t)(tid + i * 256) * 8]);
        #pragma unroll
        for (int i = 0; i < 4; ++i)
            GLD_LDS(pBs[i] + k0, &lB[(size_t)(tid + i * 256) * 8]);
        __syncthreads();

        #pragma unroll
        for (int kk = 0; kk < 2; ++kk) {
            bf16x8 af[4], bfr[4];
            #pragma unroll
            for (int m = 0; m < 4; ++m) {
                int ar = wr * 64 + m * 16 + (l & 15);
                int gran = (kk * 4 + (l >> 4)) ^ (ar & 7);
                af[m] = *(const bf16x8*)&lA[ar * 64 + gran * 8];
            }
            #pragma unroll
            for (int n = 0; n < 4; ++n) {
                int br = wc * 64 + n * 16 + (l & 15);
                int gran = (kk * 4 + (l >> 4)) ^ (br & 7);
                bfr[n] = *(const bf16x8*)&lB[br * 64 + gran * 8];
            }
            #pragma unroll
            for (int m = 0; m < 4; ++m)
                #pragma unroll
                for (int n = 0; n < 4; ++n)
                    acc[m][n] = __builtin_amdgcn_mfma_f32_16x16x32_bf16(af[m], bfr[n], acc[m][n], 0, 0, 0);
        }
        __syncthreads();
    }

    const int cbase = n0 + wc * 64 + (l & 15);
    const int rbase = m0 + wr * 64 + ((l >> 4) << 2);
    if (EPI == 0) {
        unsigned short* C = (unsigned short*)Cv;
        #pragma unroll
        for (int m = 0; m < 4; ++m) {
            #pragma unroll
            for (int j = 0; j < 4; ++j) {
                int row = rbase + m * 16 + j;
                if (row < M) {
                    const float* grow = bias + (size_t)batch[row] * HIDDEN;
                    #pragma unroll
                    for (int n = 0; n < 4; ++n) {
                        int c = cbase + n * 16;
                        float v = acc[m][n][j] + grow[c];
                        v = fmaxf(v, 0.0f);
                        C[(size_t)row * N + c] = f2bf(v);
                    }
                }
            }
        }
    } else {
        float* C = (float*)Cv;
        #pragma unroll
        for (int m = 0; m < 4; ++m) {
            #pragma unroll
            for (int j = 0; j < 4; ++j) {
                int row = rbase + m * 16 + j;
                if (row < M) {
                    #pragma unroll
                    for (int n = 0; n < 4; ++n) {
                        int c = cbase + n * 16;
                        C[(size_t)row * N + c] = acc[m][n][j] + bias[c];
                    }
                }
            }
        }
    }
}

extern "C" void kernel_launch(void* const* d_in, const int* in_sizes, int n_in,
                              void* d_out, int out_size, void* d_ws, size_t ws_size,
                              hipStream_t stream)
{
    const float* x         = (const float*)d_in[0];
    const int*   src       = (const int*)d_in[1];     // row 0 = src
    const float* edge_attr = (const float*)d_in[2];
    const float* u         = (const float*)d_in[3];
    const int*   batch     = (const int*)d_in[4];
    const float* W1        = (const float*)d_in[5];
    const float* b1        = (const float*)d_in[6];
    const float* W2        = (const float*)d_in[7];
    const float* b2        = (const float*)d_in[8];
    float* out = (float*)d_out;

    char* ws = (char*)d_ws;
    int*            cnt    = (int*)(ws);                       //    200,000 B
    int*            perm   = (int*)(ws + 200704);              // 12,800,000 B
    unsigned short* comb   = (unsigned short*)(ws + 13000704); // 32,000,000 B  [NN,320]
    unsigned short* W1T    = (unsigned short*)(ws + 45000704); //    327,680 B  [512,320]
    unsigned short* W2T    = (unsigned short*)(ws + 45328384); //    262,144 B  [256,512]
    float*          G      = (float*)(ws + 45590528);          //    131,072 B  [64,512]
    unsigned short* h      = (unsigned short*)(ws + 45721600); // 51,200,000 B  (end ~97 MB)

    prep<<<(PREP_Z + 255) / 256, 256, 0, stream>>>(W1, W2, u, b1, W1T, W2T, G, cnt);

    fillx<<<2048, 256, 0, stream>>>(src, cnt, perm, x, comb);

    seg<<<(NN + 3) / 4, 256, 0, stream>>>(edge_attr, perm, cnt, comb);

    gemm_bt_128<0><<<dim3(HIDDEN / 128, (NN + 127) / 128), 256, 0, stream>>>(
        comb, W1T, G, batch, h, NN, HIDDEN, K1);
    gemm_bt_128<1><<<dim3(NODE_OUT / 128, (NN + 127) / 128), 256, 0, stream>>>(
        h, W2T, b2, nullptr, out, NN, NODE_OUT, HIDDEN);
}